// Round 1
// baseline (109.756 us; speedup 1.0000x reference)
//
#include <hip/hip_runtime.h>

// Problem dims (fixed by setup_inputs): feat [B,H,W,D,F] float32
#define BB 32
#define HH 128
#define WW 128
#define DD 16
#define FF 8
// floats per (b,h,w) row = DD*FF = 128 -> 32 float4 per row
#define VEC_PER_ROW 32
#define HW (HH * WW)
#define TOTAL_VEC (BB * HW * VEC_PER_ROW)   // 16,777,216 float4

// ---------------------------------------------------------------------------
// Kernel 1: build the (h,w)->source-row map. One entry per output (h,w):
//   map[h*W+w] = yi*W + xi   (source plane index)  or  -1 if rotation-invalid.
// Composition (output -> input): flip2 -> roll -> rotate.
// Float math replicates the reference EXACTLY:
//   c = float(cos(deg2rad(deg)))  [double trig, cast to f32]
//   xs = c*(j-xc) + s*(i-yc) + xc   in pure f32, NO fma contraction
//   round half-to-even (np.round semantics) via rintf.
// ---------------------------------------------------------------------------
__global__ void build_map_kernel(const int* __restrict__ rot_deg,
                                 const int* __restrict__ shift_h,
                                 const int* __restrict__ shift_w,
                                 const int* __restrict__ flip2,
                                 int* __restrict__ map) {
    int idx = blockIdx.x * blockDim.x + threadIdx.x;
    if (idx >= HW) return;
    int h = idx >> 7;        // / WW
    int w = idx & (WW - 1);

    int sh = *shift_h;
    int sw = *shift_w;
    int f2 = *flip2;

    double th = (double)(*rot_deg) * (3.14159265358979323846 / 180.0);
    float c = (float)cos(th);
    float s = (float)sin(th);
    const float xc = (float)(WW - 1) * 0.5f;
    const float yc = (float)(HH - 1) * 0.5f;

    // inverse of flip(axis=W) then inverse of roll
    int i  = (h - sh) & (HH - 1);              // row into rotated image
    int w1 = f2 ? (WW - 1 - w) : w;
    int j  = (w1 - sw) & (WW - 1);             // col into rotated image

    float dx = (float)j - xc;
    float dy = (float)i - yc;
    // xs = c*dx + s*dy + xc ; ys = (-s)*dx + c*dy + yc  (pure f32 ops, no FMA)
    float xs = __fadd_rn(__fadd_rn(__fmul_rn(c, dx), __fmul_rn(s, dy)), xc);
    float ys = __fadd_rn(__fadd_rn(__fmul_rn(-s, dx), __fmul_rn(c, dy)), yc);
    int xi = (int)rintf(xs);   // round half-to-even == np.round
    int yi = (int)rintf(ys);
    bool valid = (xi >= 0) && (xi < WW) && (yi >= 0) && (yi < HH);
    map[idx] = valid ? (yi * WW + xi) : -1;
}

// ---------------------------------------------------------------------------
// Kernel 2: row gather. Each thread moves one float4. 32 consecutive threads
// move one contiguous 512 B row -> coalesced reads AND writes.
// flip3 reverses D within the row at float4 granularity (F=8 floats = 2 vec4
// per d-slot, so a float4 never straddles a d boundary).
// ---------------------------------------------------------------------------
__global__ void gather_kernel(const float4* __restrict__ src,
                              float4* __restrict__ dst,
                              const int* __restrict__ map,
                              const int* __restrict__ flip3) {
    int f3 = *flip3;
    int stride = gridDim.x * blockDim.x;
    for (int t = blockIdx.x * blockDim.x + threadIdx.x; t < TOTAL_VEC; t += stride) {
        int k  = t & (VEC_PER_ROW - 1);   // float4 index within row
        int r  = t >> 5;                  // output row = b*HW + hw
        int hw = r & (HW - 1);
        int m  = map[hw];                 // broadcast load, L1/L2 hit
        float4 v = make_float4(0.f, 0.f, 0.f, 0.f);
        if (m >= 0) {
            int kk = f3 ? ((((DD - 1) - (k >> 1)) << 1) | (k & 1)) : k;
            v = src[(((size_t)(r - hw + m)) << 5) + (size_t)kk];
        }
        dst[t] = v;
    }
}

// ---------------------------------------------------------------------------
// Fallback (only if ws_size is too small for the 64 KB map): compute the
// mapping inline per thread. Slower (per-thread double trig) but correct.
// ---------------------------------------------------------------------------
__global__ void gather_inline_kernel(const float4* __restrict__ src,
                                     float4* __restrict__ dst,
                                     const int* __restrict__ rot_deg,
                                     const int* __restrict__ shift_h,
                                     const int* __restrict__ shift_w,
                                     const int* __restrict__ flip2,
                                     const int* __restrict__ flip3) {
    int sh = *shift_h, sw = *shift_w, f2 = *flip2, f3 = *flip3;
    double th = (double)(*rot_deg) * (3.14159265358979323846 / 180.0);
    float c = (float)cos(th);
    float s = (float)sin(th);
    const float xc = (float)(WW - 1) * 0.5f;
    const float yc = (float)(HH - 1) * 0.5f;
    int stride = gridDim.x * blockDim.x;
    for (int t = blockIdx.x * blockDim.x + threadIdx.x; t < TOTAL_VEC; t += stride) {
        int k  = t & (VEC_PER_ROW - 1);
        int r  = t >> 5;
        int hw = r & (HW - 1);
        int h = hw >> 7, w = hw & (WW - 1);
        int i  = (h - sh) & (HH - 1);
        int w1 = f2 ? (WW - 1 - w) : w;
        int j  = (w1 - sw) & (WW - 1);
        float dx = (float)j - xc;
        float dy = (float)i - yc;
        float xs = __fadd_rn(__fadd_rn(__fmul_rn(c, dx), __fmul_rn(s, dy)), xc);
        float ys = __fadd_rn(__fadd_rn(__fmul_rn(-s, dx), __fmul_rn(c, dy)), yc);
        int xi = (int)rintf(xs);
        int yi = (int)rintf(ys);
        float4 v = make_float4(0.f, 0.f, 0.f, 0.f);
        if ((xi >= 0) && (xi < WW) && (yi >= 0) && (yi < HH)) {
            int m = yi * WW + xi;
            int kk = f3 ? ((((DD - 1) - (k >> 1)) << 1) | (k & 1)) : k;
            v = src[(((size_t)(r - hw + m)) << 5) + (size_t)kk];
        }
        dst[t] = v;
    }
}

extern "C" void kernel_launch(void* const* d_in, const int* in_sizes, int n_in,
                              void* d_out, int out_size, void* d_ws, size_t ws_size,
                              hipStream_t stream) {
    const float* feat = (const float*)d_in[0];
    const int* rot    = (const int*)d_in[1];
    const int* sh     = (const int*)d_in[2];
    const int* sw     = (const int*)d_in[3];
    const int* f2     = (const int*)d_in[4];
    const int* f3     = (const int*)d_in[5];
    float* out = (float*)d_out;

    if (ws_size >= (size_t)(HW * sizeof(int))) {
        int* map = (int*)d_ws;
        build_map_kernel<<<(HW + 255) / 256, 256, 0, stream>>>(rot, sh, sw, f2, map);
        gather_kernel<<<2048, 256, 0, stream>>>((const float4*)feat, (float4*)out, map, f3);
    } else {
        gather_inline_kernel<<<2048, 256, 0, stream>>>((const float4*)feat, (float4*)out,
                                                       rot, sh, sw, f2, f3);
    }
}